// Round 3
// baseline (120.555 us; speedup 1.0000x reference)
//
#include <hip/hip_runtime.h>

// Problem constants (match reference)
#define N_IMG 50331648    // 1024*3*128*128
#define BATCH 1024
#define DLAT  128
#define LN2   0.69314718055994530942

// ws layout: acc[0]=bce_sum (log2 domain), acc[1]=kl_sum, acc[2]=trip_sum (doubles)

// BCE element in log2 domain: lg + r*(lf - lg), lf=log2(f), lg=log2(1-f).
// __log2f -> single v_log_f32 (trans pipe).
__device__ __forceinline__ float bce2(float r, float f) {
    const float lf = __log2f(f);
    const float lg = __log2f(1.0f - f);
    return lg + r * (lf - lg);
}

// 524288 threads; 12,582,912 float4-pairs; 24 pairs/thread at stride S.
// Pipeline: 6 batches of 4 pairs, ping-pong A/B so 8 loads (8KB/wave) are
// always in flight while computing the other batch. All names static (no
// runtime-indexed arrays -> no scratch).
__global__ __launch_bounds__(256) void bce_reduce_kernel(
    const float* __restrict__ real,
    const float* __restrict__ fake,
    double* __restrict__ acc)
{
    const float4* __restrict__ r4 = reinterpret_cast<const float4*>(real);
    const float4* __restrict__ f4 = reinterpret_cast<const float4*>(fake);
    const int S   = gridDim.x * blockDim.x;            // 524288
    const int idx = blockIdx.x * blockDim.x + threadIdx.x;

    float s0 = 0.0f, s1 = 0.0f;

    float4 rA0, rA1, rA2, rA3, fA0, fA1, fA2, fA3;
    float4 rB0, rB1, rB2, rB3, fB0, fB1, fB2, fB3;

#define LDA(p0) rA0 = r4[idx + (p0)*S]; fA0 = f4[idx + (p0)*S]; \
                rA1 = r4[idx + (p0+1)*S]; fA1 = f4[idx + (p0+1)*S]; \
                rA2 = r4[idx + (p0+2)*S]; fA2 = f4[idx + (p0+2)*S]; \
                rA3 = r4[idx + (p0+3)*S]; fA3 = f4[idx + (p0+3)*S];
#define LDB(p0) rB0 = r4[idx + (p0)*S]; fB0 = f4[idx + (p0)*S]; \
                rB1 = r4[idx + (p0+1)*S]; fB1 = f4[idx + (p0+1)*S]; \
                rB2 = r4[idx + (p0+2)*S]; fB2 = f4[idx + (p0+2)*S]; \
                rB3 = r4[idx + (p0+3)*S]; fB3 = f4[idx + (p0+3)*S];
#define CP(r, f) { s0 += bce2(r.x, f.x); s1 += bce2(r.y, f.y); \
                   s0 += bce2(r.z, f.z); s1 += bce2(r.w, f.w); }
#define CPA CP(rA0, fA0) CP(rA1, fA1) CP(rA2, fA2) CP(rA3, fA3)
#define CPB CP(rB0, fB0) CP(rB1, fB1) CP(rB2, fB2) CP(rB3, fB3)

    LDA(0)            // prologue: batch A = pairs 0..3
    LDB(4)  CPA       // loads for 4..7 in flight while computing 0..3
    LDA(8)  CPB
    LDB(12) CPA
    LDA(16) CPB
    LDB(20) CPA
    CPB               // epilogue

#undef LDA
#undef LDB
#undef CP
#undef CPA
#undef CPB

    float s = s0 + s1;

    // wave-64 reduce
    #pragma unroll
    for (int o = 32; o > 0; o >>= 1) s += __shfl_down(s, o, 64);

    __shared__ float wsum[4];
    const int lane = threadIdx.x & 63;
    const int wid  = threadIdx.x >> 6;
    if (lane == 0) wsum[wid] = s;
    __syncthreads();
    if (threadIdx.x == 0) {
        float t = wsum[0] + wsum[1] + wsum[2] + wsum[3];
        atomicAdd(&acc[0], (double)t);
    }
}

__global__ __launch_bounds__(128) void latent_kernel(
    const float* __restrict__ mean, const float* __restrict__ logvar,
    const float* __restrict__ am,   const float* __restrict__ al,
    const float* __restrict__ pm,   const float* __restrict__ pl,
    const float* __restrict__ nm,   const float* __restrict__ nl,
    double* __restrict__ acc)
{
    const int b   = blockIdx.x;
    const int j   = threadIdx.x;      // 0..127 latent dim
    const int idx = b * DLAT + j;

    const float m  = mean[idx];
    const float lv = logvar[idx];
    const float kl_p = 1.0f + lv - m * m - expf(lv);

    const float amj = am[idx], alj = al[idx];
    const float pmj = pm[idx], plj = pl[idx];
    const float nmj = nm[idx], nlj = nl[idx];
    const float va  = expf(alj);

    // term_a + term_b = 2*log(vm) - la - lb + 2 + 0.5*(ma-mb)^2/vm
    const float vp   = expf(plj);
    const float vm_p = 0.25f * (va + vp);
    const float dmp  = amj - pmj;
    const float s_ap = 2.0f * logf(vm_p) - alj - plj + 2.0f + 0.5f * dmp * dmp / vm_p;

    const float vn   = expf(nlj);
    const float vm_n = 0.25f * (va + vn);
    const float dmn  = amj - nmj;
    const float s_an = 2.0f * logf(vm_n) - alj - nlj + 2.0f + 0.5f * dmn * dmn / vm_n;

    float a = s_ap, c = s_an, k = kl_p;
    #pragma unroll
    for (int o = 32; o > 0; o >>= 1) {
        a += __shfl_down(a, o, 64);
        c += __shfl_down(c, o, 64);
        k += __shfl_down(k, o, 64);
    }
    __shared__ float red[2][3];
    const int lane = threadIdx.x & 63;
    const int wid  = threadIdx.x >> 6;
    if (lane == 0) { red[wid][0] = a; red[wid][1] = c; red[wid][2] = k; }
    __syncthreads();
    if (threadIdx.x == 0) {
        const float S_ap = red[0][0] + red[1][0];
        const float S_an = red[0][1] + red[1][1];
        const float S_kl = red[0][2] + red[1][2];
        const float js_ap = 0.25f * S_ap;
        const float js_an = 0.25f * S_an;
        const float prob  = 1.0f / (1.0f + expf(js_ap - js_an));
        atomicAdd(&acc[1], (double)S_kl);
        atomicAdd(&acc[2], (double)prob);
    }
}

__global__ void finalize_kernel(const double* __restrict__ acc, float* __restrict__ out)
{
    if (threadIdx.x == 0 && blockIdx.x == 0) {
        const double recon   = -(LN2 * acc[0] / (double)N_IMG);   // log2 -> ln
        const double kl      = -0.5 * (acc[1] / (double)(BATCH * DLAT));
        const double triplet = -(acc[2] / (double)BATCH);
        out[0] = (float)(recon + kl + triplet);  // final_loss
        out[1] = (float)triplet;                 // triplet_error
        out[2] = (float)recon;                   // recon_error
        out[3] = (float)kl;                      // kl_error
    }
}

extern "C" void kernel_launch(void* const* d_in, const int* in_sizes, int n_in,
                              void* d_out, int out_size, void* d_ws, size_t ws_size,
                              hipStream_t stream)
{
    const float* real = (const float*)d_in[0];
    const float* fake = (const float*)d_in[1];
    const float* mean = (const float*)d_in[2];
    const float* logv = (const float*)d_in[3];
    const float* am   = (const float*)d_in[4];
    const float* al   = (const float*)d_in[5];
    const float* pm   = (const float*)d_in[6];
    const float* pl   = (const float*)d_in[7];
    const float* nm   = (const float*)d_in[8];
    const float* nl   = (const float*)d_in[9];
    float*  out = (float*)d_out;
    double* acc = (double*)d_ws;

    hipMemsetAsync(acc, 0, 3 * sizeof(double), stream);

    bce_reduce_kernel<<<2048, 256, 0, stream>>>(real, fake, &acc[0]);
    latent_kernel<<<BATCH, DLAT, 0, stream>>>(mean, logv, am, al, pm, pl, nm, nl, acc);
    finalize_kernel<<<1, 64, 0, stream>>>(acc, out);
}

// Round 4
// 120.040 us; speedup vs baseline: 1.0043x; 1.0043x over previous
//
#include <hip/hip_runtime.h>

// Problem constants (match reference)
#define N_IMG 50331648    // 1024*3*128*128
#define BATCH 1024
#define DLAT  128
#define LN2   0.69314718055994530942

// ws layout: acc[0]=bce_sum (log2 domain), acc[1]=kl_sum, acc[2]=trip_sum (doubles)

// BCE element in log2 domain: lg + r*(lf - lg), lf=log2(f), lg=log2(1-f).
// __log2f -> single v_log_f32 (trans pipe).
__device__ __forceinline__ float bce2(float r, float f) {
    const float lf = __log2f(f);
    const float lg = __log2f(1.0f - f);
    return lg + r * (lf - lg);
}

// Scheduling fence: forbid the compiler from moving ANY instruction across.
// R3 post-mortem: without this, hipcc sinks each load to just before its use
// (VGPR stayed 36), destroying the software pipeline and serializing on
// memory latency.
#define SB __builtin_amdgcn_sched_barrier(0);

// 524288 threads; 12,582,912 float4-pairs; 24 pairs/thread at stride S.
// Ping-pong pipeline: batches of 4 pairs (8 x global_load_dwordx4 = 8KB/wave
// in flight) pinned with sched_barrier so batch B's loads are issued BEFORE
// batch A's compute. Compiler then emits counted vmcnt waits (B stays in
// flight during CPA).
__global__ __launch_bounds__(256) void bce_reduce_kernel(
    const float* __restrict__ real,
    const float* __restrict__ fake,
    double* __restrict__ acc)
{
    const float4* __restrict__ r4 = reinterpret_cast<const float4*>(real);
    const float4* __restrict__ f4 = reinterpret_cast<const float4*>(fake);
    const int S   = gridDim.x * blockDim.x;            // 524288
    const int idx = blockIdx.x * blockDim.x + threadIdx.x;

    float s0 = 0.0f, s1 = 0.0f;

    float4 rA0, rA1, rA2, rA3, fA0, fA1, fA2, fA3;
    float4 rB0, rB1, rB2, rB3, fB0, fB1, fB2, fB3;

#define LDA(p0) rA0 = r4[idx + (p0)*S]; fA0 = f4[idx + (p0)*S]; \
                rA1 = r4[idx + (p0+1)*S]; fA1 = f4[idx + (p0+1)*S]; \
                rA2 = r4[idx + (p0+2)*S]; fA2 = f4[idx + (p0+2)*S]; \
                rA3 = r4[idx + (p0+3)*S]; fA3 = f4[idx + (p0+3)*S];
#define LDB(p0) rB0 = r4[idx + (p0)*S]; fB0 = f4[idx + (p0)*S]; \
                rB1 = r4[idx + (p0+1)*S]; fB1 = f4[idx + (p0+1)*S]; \
                rB2 = r4[idx + (p0+2)*S]; fB2 = f4[idx + (p0+2)*S]; \
                rB3 = r4[idx + (p0+3)*S]; fB3 = f4[idx + (p0+3)*S];
#define CP(r, f) { s0 += bce2(r.x, f.x); s1 += bce2(r.y, f.y); \
                   s0 += bce2(r.z, f.z); s1 += bce2(r.w, f.w); }
#define CPA CP(rA0, fA0) CP(rA1, fA1) CP(rA2, fA2) CP(rA3, fA3)
#define CPB CP(rB0, fB0) CP(rB1, fB1) CP(rB2, fB2) CP(rB3, fB3)

    LDA(0)  SB            // prologue: issue batch A (pairs 0..3)
    LDB(4)  SB CPA SB     // issue B(4..7) BEFORE computing A(0..3)
    LDA(8)  SB CPB SB
    LDB(12) SB CPA SB
    LDA(16) SB CPB SB
    LDB(20) SB CPA SB
    CPB                   // epilogue

#undef LDA
#undef LDB
#undef CP
#undef CPA
#undef CPB

    float s = s0 + s1;

    // wave-64 reduce
    #pragma unroll
    for (int o = 32; o > 0; o >>= 1) s += __shfl_down(s, o, 64);

    __shared__ float wsum[4];
    const int lane = threadIdx.x & 63;
    const int wid  = threadIdx.x >> 6;
    if (lane == 0) wsum[wid] = s;
    __syncthreads();
    if (threadIdx.x == 0) {
        float t = wsum[0] + wsum[1] + wsum[2] + wsum[3];
        atomicAdd(&acc[0], (double)t);
    }
}

__global__ __launch_bounds__(128) void latent_kernel(
    const float* __restrict__ mean, const float* __restrict__ logvar,
    const float* __restrict__ am,   const float* __restrict__ al,
    const float* __restrict__ pm,   const float* __restrict__ pl,
    const float* __restrict__ nm,   const float* __restrict__ nl,
    double* __restrict__ acc)
{
    const int b   = blockIdx.x;
    const int j   = threadIdx.x;      // 0..127 latent dim
    const int idx = b * DLAT + j;

    const float m  = mean[idx];
    const float lv = logvar[idx];
    const float kl_p = 1.0f + lv - m * m - expf(lv);

    const float amj = am[idx], alj = al[idx];
    const float pmj = pm[idx], plj = pl[idx];
    const float nmj = nm[idx], nlj = nl[idx];
    const float va  = expf(alj);

    // term_a + term_b = 2*log(vm) - la - lb + 2 + 0.5*(ma-mb)^2/vm
    const float vp   = expf(plj);
    const float vm_p = 0.25f * (va + vp);
    const float dmp  = amj - pmj;
    const float s_ap = 2.0f * logf(vm_p) - alj - plj + 2.0f + 0.5f * dmp * dmp / vm_p;

    const float vn   = expf(nlj);
    const float vm_n = 0.25f * (va + vn);
    const float dmn  = amj - nmj;
    const float s_an = 2.0f * logf(vm_n) - alj - nlj + 2.0f + 0.5f * dmn * dmn / vm_n;

    float a = s_ap, c = s_an, k = kl_p;
    #pragma unroll
    for (int o = 32; o > 0; o >>= 1) {
        a += __shfl_down(a, o, 64);
        c += __shfl_down(c, o, 64);
        k += __shfl_down(k, o, 64);
    }
    __shared__ float red[2][3];
    const int lane = threadIdx.x & 63;
    const int wid  = threadIdx.x >> 6;
    if (lane == 0) { red[wid][0] = a; red[wid][1] = c; red[wid][2] = k; }
    __syncthreads();
    if (threadIdx.x == 0) {
        const float S_ap = red[0][0] + red[1][0];
        const float S_an = red[0][1] + red[1][1];
        const float S_kl = red[0][2] + red[1][2];
        const float js_ap = 0.25f * S_ap;
        const float js_an = 0.25f * S_an;
        const float prob  = 1.0f / (1.0f + expf(js_ap - js_an));
        atomicAdd(&acc[1], (double)S_kl);
        atomicAdd(&acc[2], (double)prob);
    }
}

__global__ void finalize_kernel(const double* __restrict__ acc, float* __restrict__ out)
{
    if (threadIdx.x == 0 && blockIdx.x == 0) {
        const double recon   = -(LN2 * acc[0] / (double)N_IMG);   // log2 -> ln
        const double kl      = -0.5 * (acc[1] / (double)(BATCH * DLAT));
        const double triplet = -(acc[2] / (double)BATCH);
        out[0] = (float)(recon + kl + triplet);  // final_loss
        out[1] = (float)triplet;                 // triplet_error
        out[2] = (float)recon;                   // recon_error
        out[3] = (float)kl;                      // kl_error
    }
}

extern "C" void kernel_launch(void* const* d_in, const int* in_sizes, int n_in,
                              void* d_out, int out_size, void* d_ws, size_t ws_size,
                              hipStream_t stream)
{
    const float* real = (const float*)d_in[0];
    const float* fake = (const float*)d_in[1];
    const float* mean = (const float*)d_in[2];
    const float* logv = (const float*)d_in[3];
    const float* am   = (const float*)d_in[4];
    const float* al   = (const float*)d_in[5];
    const float* pm   = (const float*)d_in[6];
    const float* pl   = (const float*)d_in[7];
    const float* nm   = (const float*)d_in[8];
    const float* nl   = (const float*)d_in[9];
    float*  out = (float*)d_out;
    double* acc = (double*)d_ws;

    hipMemsetAsync(acc, 0, 3 * sizeof(double), stream);

    bce_reduce_kernel<<<2048, 256, 0, stream>>>(real, fake, &acc[0]);
    latent_kernel<<<BATCH, DLAT, 0, stream>>>(mean, logv, am, al, pm, pl, nm, nl, acc);
    finalize_kernel<<<1, 64, 0, stream>>>(acc, out);
}

// Round 6
// 109.098 us; speedup vs baseline: 1.1050x; 1.1003x over previous
//
#include <hip/hip_runtime.h>

// Problem constants (match reference)
#define N_IMG 50331648    // 1024*3*128*128 elements per image tensor
#define BATCH 1024
#define DLAT  128
#define LN2   0.69314718055994530942

typedef float f32x4 __attribute__((ext_vector_type(4)));

// ws layout: acc[0]=bce_sum (log2 domain), acc[1]=kl_sum, acc[2]=trip_sum (doubles)

// BCE element in log2 domain: lg + r*(lf - lg), lf=log2(f), lg=log2(1-f).
__device__ __forceinline__ float bce2(float r, float f) {
    const float lf = __log2f(f);
    const float lg = __log2f(1.0f - f);
    return lg + r * (lf - lg);
}

// R5 post-mortem: "=v" outputs let LLVM alias an output VGPR with the voff
// input; async load-return clobbered voff mid-block -> OOB -> inf. Outputs
// MUST be early-clobber "=&v" (they are written asynchronously, after the
// asm block retires). Also launch_bounds(256,6) capped VGPR at ~85 ->
// spill risk on async outputs; relaxed to (256,4) (cap 128).
#define ISSUE(r0,r1,r2,r3,g0,g1,g2,g3)                      \
  asm volatile(                                             \
    "global_load_dwordx4 %0, %8, %9 offset:0\n\t"           \
    "global_load_dwordx4 %1, %8, %9 offset:1024\n\t"        \
    "global_load_dwordx4 %2, %8, %9 offset:2048\n\t"        \
    "global_load_dwordx4 %3, %8, %9 offset:3072\n\t"        \
    "global_load_dwordx4 %4, %8, %10 offset:0\n\t"          \
    "global_load_dwordx4 %5, %8, %10 offset:1024\n\t"       \
    "global_load_dwordx4 %6, %8, %10 offset:2048\n\t"       \
    "global_load_dwordx4 %7, %8, %10 offset:3072"           \
    : "=&v"(r0), "=&v"(r1), "=&v"(r2), "=&v"(r3),           \
      "=&v"(g0), "=&v"(g1), "=&v"(g2), "=&v"(g3)            \
    : "v"(voff), "s"(realp), "s"(fakep)                     \
    : "memory")

// rule #18: sched_barrier(0) immediately after an inline-asm waitcnt, else
// hipcc hoists register-only compute past it.
#define WAIT8 { asm volatile("s_waitcnt vmcnt(8)" ::: "memory"); \
                __builtin_amdgcn_sched_barrier(0); }
#define WAIT0 { asm volatile("s_waitcnt vmcnt(0)" ::: "memory"); \
                __builtin_amdgcn_sched_barrier(0); }

__global__ __launch_bounds__(256, 4) void bce_reduce_kernel(
    const float* __restrict__ real,
    const float* __restrict__ fake,
    double* __restrict__ acc)
{
    const int lane = threadIdx.x & 63;
    const int wid  = threadIdx.x >> 6;
    const int wave_gid = blockIdx.x * 4 + wid;          // 0..6143 (1536 blocks)
    unsigned int voff = (unsigned int)wave_gid * 32768u + (unsigned int)lane * 16u;

    const float* realp = real;
    const float* fakep = fake;

    float s0 = 0.0f, s1 = 0.0f;

    f32x4 rA0, rA1, rA2, rA3, fA0, fA1, fA2, fA3;
    f32x4 rB0, rB1, rB2, rB3, fB0, fB1, fB2, fB3;

#define CP(r, f) { s0 += bce2(r[0], f[0]); s1 += bce2(r[1], f[1]); \
                   s0 += bce2(r[2], f[2]); s1 += bce2(r[3], f[3]); }
#define CPA CP(rA0, fA0) CP(rA1, fA1) CP(rA2, fA2) CP(rA3, fA3)
#define CPB CP(rB0, fB0) CP(rB1, fB1) CP(rB2, fB2) CP(rB3, fB3)
#define ISSUE_A ISSUE(rA0, rA1, rA2, rA3, fA0, fA1, fA2, fA3)
#define ISSUE_B ISSUE(rB0, rB1, rB2, rB3, fB0, fB1, fB2, fB3)

    ISSUE_A; voff += 4096u;             // batch 0 in flight (8 loads)
    ISSUE_B; voff += 4096u;             // batch 1 in flight (16 loads)
    WAIT8 CPA ISSUE_A; voff += 4096u;   // compute 0, issue 2
    WAIT8 CPB ISSUE_B; voff += 4096u;   // compute 1, issue 3
    WAIT8 CPA ISSUE_A; voff += 4096u;   // compute 2, issue 4
    WAIT8 CPB ISSUE_B; voff += 4096u;   // compute 3, issue 5
    WAIT8 CPA ISSUE_A; voff += 4096u;   // compute 4, issue 6
    WAIT8 CPB ISSUE_B;                  // compute 5, issue 7
    WAIT8 CPA                           // compute 6
    WAIT0 CPB                           // compute 7

#undef CP
#undef CPA
#undef CPB
#undef ISSUE_A
#undef ISSUE_B

    float s = s0 + s1;

    // wave-64 reduce
    #pragma unroll
    for (int o = 32; o > 0; o >>= 1) s += __shfl_down(s, o, 64);

    __shared__ float wsum[4];
    if (lane == 0) wsum[wid] = s;
    __syncthreads();
    if (threadIdx.x == 0) {
        float t = wsum[0] + wsum[1] + wsum[2] + wsum[3];
        atomicAdd(&acc[0], (double)t);
    }
}

__global__ __launch_bounds__(128) void latent_kernel(
    const float* __restrict__ mean, const float* __restrict__ logvar,
    const float* __restrict__ am,   const float* __restrict__ al,
    const float* __restrict__ pm,   const float* __restrict__ pl,
    const float* __restrict__ nm,   const float* __restrict__ nl,
    double* __restrict__ acc)
{
    const int b   = blockIdx.x;
    const int j   = threadIdx.x;      // 0..127 latent dim
    const int idx = b * DLAT + j;

    const float m  = mean[idx];
    const float lv = logvar[idx];
    const float kl_p = 1.0f + lv - m * m - expf(lv);

    const float amj = am[idx], alj = al[idx];
    const float pmj = pm[idx], plj = pl[idx];
    const float nmj = nm[idx], nlj = nl[idx];
    const float va  = expf(alj);

    // term_a + term_b = 2*log(vm) - la - lb + 2 + 0.5*(ma-mb)^2/vm
    const float vp   = expf(plj);
    const float vm_p = 0.25f * (va + vp);
    const float dmp  = amj - pmj;
    const float s_ap = 2.0f * logf(vm_p) - alj - plj + 2.0f + 0.5f * dmp * dmp / vm_p;

    const float vn   = expf(nlj);
    const float vm_n = 0.25f * (va + vn);
    const float dmn  = amj - nmj;
    const float s_an = 2.0f * logf(vm_n) - alj - nlj + 2.0f + 0.5f * dmn * dmn / vm_n;

    float a = s_ap, c = s_an, k = kl_p;
    #pragma unroll
    for (int o = 32; o > 0; o >>= 1) {
        a += __shfl_down(a, o, 64);
        c += __shfl_down(c, o, 64);
        k += __shfl_down(k, o, 64);
    }
    __shared__ float red[2][3];
    const int lane = threadIdx.x & 63;
    const int wid  = threadIdx.x >> 6;
    if (lane == 0) { red[wid][0] = a; red[wid][1] = c; red[wid][2] = k; }
    __syncthreads();
    if (threadIdx.x == 0) {
        const float S_ap = red[0][0] + red[1][0];
        const float S_an = red[0][1] + red[1][1];
        const float S_kl = red[0][2] + red[1][2];
        const float js_ap = 0.25f * S_ap;
        const float js_an = 0.25f * S_an;
        const float prob  = 1.0f / (1.0f + expf(js_ap - js_an));
        atomicAdd(&acc[1], (double)S_kl);
        atomicAdd(&acc[2], (double)prob);
    }
}

__global__ void finalize_kernel(const double* __restrict__ acc, float* __restrict__ out)
{
    if (threadIdx.x == 0 && blockIdx.x == 0) {
        const double recon   = -(LN2 * acc[0] / (double)N_IMG);   // log2 -> ln
        const double kl      = -0.5 * (acc[1] / (double)(BATCH * DLAT));
        const double triplet = -(acc[2] / (double)BATCH);
        out[0] = (float)(recon + kl + triplet);  // final_loss
        out[1] = (float)triplet;                 // triplet_error
        out[2] = (float)recon;                   // recon_error
        out[3] = (float)kl;                      // kl_error
    }
}

extern "C" void kernel_launch(void* const* d_in, const int* in_sizes, int n_in,
                              void* d_out, int out_size, void* d_ws, size_t ws_size,
                              hipStream_t stream)
{
    const float* real = (const float*)d_in[0];
    const float* fake = (const float*)d_in[1];
    const float* mean = (const float*)d_in[2];
    const float* logv = (const float*)d_in[3];
    const float* am   = (const float*)d_in[4];
    const float* al   = (const float*)d_in[5];
    const float* pm   = (const float*)d_in[6];
    const float* pl   = (const float*)d_in[7];
    const float* nm   = (const float*)d_in[8];
    const float* nl   = (const float*)d_in[9];
    float*  out = (float*)d_out;
    double* acc = (double*)d_ws;

    hipMemsetAsync(acc, 0, 3 * sizeof(double), stream);

    // 1536 blocks x 4 waves = 6144 waves x 32KB/stream = exactly 2 x 201.3MB.
    bce_reduce_kernel<<<1536, 256, 0, stream>>>(real, fake, &acc[0]);
    latent_kernel<<<BATCH, DLAT, 0, stream>>>(mean, logv, am, al, pm, pl, nm, nl, acc);
    finalize_kernel<<<1, 64, 0, stream>>>(acc, out);
}

// Round 8
// 101.199 us; speedup vs baseline: 1.1913x; 1.0780x over previous
//
#include <hip/hip_runtime.h>

// Problem constants (match reference)
#define N_IMG 50331648    // 1024*3*128*128 elements per image tensor
#define BATCH 1024
#define DLAT  128
#define LN2   0.69314718055994530942

// clang ext_vector_type works with __builtin_nontemporal_load (HIP_vector_type does not)
typedef float f32x4 __attribute__((ext_vector_type(4)));

// ws layout: acc[0]=bce_sum (log2 domain), acc[1]=kl_sum, acc[2]=trip_sum (doubles)

// BCE element in log2 domain: lg + r*(lf - lg), lf=log2(f), lg=log2(1-f).
// __log2f -> single v_log_f32 (trans pipe).
__device__ __forceinline__ float bce2(float r, float f) {
    const float lf = __log2f(f);
    const float lg = __log2f(1.0f - f);
    return lg + r * (lf - lg);
}

// R6 post-mortem: three structurally different kernels (naive grid-stride,
// reduced-VALU, forced inline-asm 16-deep pipeline) all saturate at the same
// 3.0 TB/s app read BW (1.5 TB/s HBM + 1.5 TB/s L3 hits, 50/50 split).
// Latency self-inflates to match a saturated service path -> more MLP is
// useless. Hypothesis: the L3 controller serves BOTH the hit and miss
// streams and is the ~3 TB/s choke point.
//
// This round: cache-partition the two streams. real_data loads are
// NON-TEMPORAL (nt flag, no L3 allocation) -> fake_data (201 MB < 256 MB L3)
// becomes fully L3-resident across replays; real_data streams pure HBM.
// The two paths then serve disjoint streams concurrently.
__global__ __launch_bounds__(256) void bce_reduce_kernel(
    const float* __restrict__ real,
    const float* __restrict__ fake,
    double* __restrict__ acc)
{
    const f32x4* __restrict__ r4 = reinterpret_cast<const f32x4*>(real);
    const f32x4* __restrict__ f4 = reinterpret_cast<const f32x4*>(fake);
    const int S   = gridDim.x * blockDim.x;            // 524288
    const int idx = blockIdx.x * blockDim.x + threadIdx.x;

    float s0 = 0.0f, s1 = 0.0f;
    // 12,582,912 float4-pairs; 24 pairs/thread; 2 pairs/iter for mild ILP.
    #pragma unroll 2
    for (int it = 0; it < 12; ++it) {
        const int i = idx + it * 2 * S;
        const f32x4 ra = __builtin_nontemporal_load(&r4[i]);      // NT: bypass L3 alloc
        const f32x4 fa = f4[i];                                   // cached: L3-resident
        const f32x4 rb = __builtin_nontemporal_load(&r4[i + S]);
        const f32x4 fb = f4[i + S];
        s0 += bce2(ra[0], fa[0]);
        s1 += bce2(ra[1], fa[1]);
        s0 += bce2(ra[2], fa[2]);
        s1 += bce2(ra[3], fa[3]);
        s0 += bce2(rb[0], fb[0]);
        s1 += bce2(rb[1], fb[1]);
        s0 += bce2(rb[2], fb[2]);
        s1 += bce2(rb[3], fb[3]);
    }
    float s = s0 + s1;

    // wave-64 reduce
    #pragma unroll
    for (int o = 32; o > 0; o >>= 1) s += __shfl_down(s, o, 64);

    __shared__ float wsum[4];
    const int lane = threadIdx.x & 63;
    const int wid  = threadIdx.x >> 6;
    if (lane == 0) wsum[wid] = s;
    __syncthreads();
    if (threadIdx.x == 0) {
        float t = wsum[0] + wsum[1] + wsum[2] + wsum[3];
        atomicAdd(&acc[0], (double)t);
    }
}

__global__ __launch_bounds__(128) void latent_kernel(
    const float* __restrict__ mean, const float* __restrict__ logvar,
    const float* __restrict__ am,   const float* __restrict__ al,
    const float* __restrict__ pm,   const float* __restrict__ pl,
    const float* __restrict__ nm,   const float* __restrict__ nl,
    double* __restrict__ acc)
{
    const int b   = blockIdx.x;
    const int j   = threadIdx.x;      // 0..127 latent dim
    const int idx = b * DLAT + j;

    const float m  = mean[idx];
    const float lv = logvar[idx];
    const float kl_p = 1.0f + lv - m * m - expf(lv);

    const float amj = am[idx], alj = al[idx];
    const float pmj = pm[idx], plj = pl[idx];
    const float nmj = nm[idx], nlj = nl[idx];
    const float va  = expf(alj);

    // term_a + term_b = 2*log(vm) - la - lb + 2 + 0.5*(ma-mb)^2/vm
    const float vp   = expf(plj);
    const float vm_p = 0.25f * (va + vp);
    const float dmp  = amj - pmj;
    const float s_ap = 2.0f * logf(vm_p) - alj - plj + 2.0f + 0.5f * dmp * dmp / vm_p;

    const float vn   = expf(nlj);
    const float vm_n = 0.25f * (va + vn);
    const float dmn  = amj - nmj;
    const float s_an = 2.0f * logf(vm_n) - alj - nlj + 2.0f + 0.5f * dmn * dmn / vm_n;

    float a = s_ap, c = s_an, k = kl_p;
    #pragma unroll
    for (int o = 32; o > 0; o >>= 1) {
        a += __shfl_down(a, o, 64);
        c += __shfl_down(c, o, 64);
        k += __shfl_down(k, o, 64);
    }
    __shared__ float red[2][3];
    const int lane = threadIdx.x & 63;
    const int wid  = threadIdx.x >> 6;
    if (lane == 0) { red[wid][0] = a; red[wid][1] = c; red[wid][2] = k; }
    __syncthreads();
    if (threadIdx.x == 0) {
        const float S_ap = red[0][0] + red[1][0];
        const float S_an = red[0][1] + red[1][1];
        const float S_kl = red[0][2] + red[1][2];
        const float js_ap = 0.25f * S_ap;
        const float js_an = 0.25f * S_an;
        const float prob  = 1.0f / (1.0f + expf(js_ap - js_an));
        atomicAdd(&acc[1], (double)S_kl);
        atomicAdd(&acc[2], (double)prob);
    }
}

__global__ void finalize_kernel(const double* __restrict__ acc, float* __restrict__ out)
{
    if (threadIdx.x == 0 && blockIdx.x == 0) {
        const double recon   = -(LN2 * acc[0] / (double)N_IMG);   // log2 -> ln
        const double kl      = -0.5 * (acc[1] / (double)(BATCH * DLAT));
        const double triplet = -(acc[2] / (double)BATCH);
        out[0] = (float)(recon + kl + triplet);  // final_loss
        out[1] = (float)triplet;                 // triplet_error
        out[2] = (float)recon;                   // recon_error
        out[3] = (float)kl;                      // kl_error
    }
}

extern "C" void kernel_launch(void* const* d_in, const int* in_sizes, int n_in,
                              void* d_out, int out_size, void* d_ws, size_t ws_size,
                              hipStream_t stream)
{
    const float* real = (const float*)d_in[0];
    const float* fake = (const float*)d_in[1];
    const float* mean = (const float*)d_in[2];
    const float* logv = (const float*)d_in[3];
    const float* am   = (const float*)d_in[4];
    const float* al   = (const float*)d_in[5];
    const float* pm   = (const float*)d_in[6];
    const float* pl   = (const float*)d_in[7];
    const float* nm   = (const float*)d_in[8];
    const float* nl   = (const float*)d_in[9];
    float*  out = (float*)d_out;
    double* acc = (double*)d_ws;

    (void)hipMemsetAsync(acc, 0, 3 * sizeof(double), stream);

    bce_reduce_kernel<<<2048, 256, 0, stream>>>(real, fake, &acc[0]);
    latent_kernel<<<BATCH, DLAT, 0, stream>>>(mean, logv, am, al, pm, pl, nm, nl, acc);
    finalize_kernel<<<1, 64, 0, stream>>>(acc, out);
}

// Round 10
// 98.230 us; speedup vs baseline: 1.2273x; 1.0302x over previous
//
#include <hip/hip_runtime.h>

// Problem constants (match reference)
#define N_IMG 50331648    // 1024*3*128*128 elements per image tensor
#define BATCH 1024
#define DLAT  128
#define LN2   0.69314718055994530942

typedef float f32x4 __attribute__((ext_vector_type(4)));

// ws layout: acc[0]=bce_sum (log2 domain), acc[1]=kl_sum, acc[2]=trip_sum (doubles)

// BCE element in log2 domain: lg + r*(lf - lg), lf=log2(f), lg=log2(1-f).
__device__ __forceinline__ float bce2(float r, float f) {
    const float lf = __log2f(f);
    const float lg = __log2f(1.0f - f);
    return lg + r * (lf - lg);
}

// R9 post-mortem: NT on BOTH streams -> replay-nondeterministic inf (NT read
// of fake transiently returned non-input data). Empirical rule: NT on real
// only is safe (R8 passed, +8%). R6's forced-MLP asm pipeline was neutral
// PRE-partitioning (L3 thrash was the limiter then). This round combines
// them: 16-deep asm ping-pong + nt cache policy on the real stream only.
// real streams pure HBM with deep queues; fake stays L3-resident.
#define ISSUE(r0,r1,r2,r3,g0,g1,g2,g3)                      \
  asm volatile(                                             \
    "global_load_dwordx4 %0, %8, %9 offset:0 nt\n\t"        \
    "global_load_dwordx4 %1, %8, %9 offset:1024 nt\n\t"     \
    "global_load_dwordx4 %2, %8, %9 offset:2048 nt\n\t"     \
    "global_load_dwordx4 %3, %8, %9 offset:3072 nt\n\t"     \
    "global_load_dwordx4 %4, %8, %10 offset:0\n\t"          \
    "global_load_dwordx4 %5, %8, %10 offset:1024\n\t"       \
    "global_load_dwordx4 %6, %8, %10 offset:2048\n\t"       \
    "global_load_dwordx4 %7, %8, %10 offset:3072"           \
    : "=&v"(r0), "=&v"(r1), "=&v"(r2), "=&v"(r3),           \
      "=&v"(g0), "=&v"(g1), "=&v"(g2), "=&v"(g3)            \
    : "v"(voff), "s"(realp), "s"(fakep)                     \
    : "memory")

// rule #18: sched_barrier(0) immediately after an inline-asm waitcnt.
#define WAIT8 { asm volatile("s_waitcnt vmcnt(8)" ::: "memory"); \
                __builtin_amdgcn_sched_barrier(0); }
#define WAIT0 { asm volatile("s_waitcnt vmcnt(0)" ::: "memory"); \
                __builtin_amdgcn_sched_barrier(0); }

__global__ __launch_bounds__(256, 4) void bce_reduce_kernel(
    const float* __restrict__ real,
    const float* __restrict__ fake,
    double* __restrict__ acc)
{
    const int lane = threadIdx.x & 63;
    const int wid  = threadIdx.x >> 6;
    const int wave_gid = blockIdx.x * 4 + wid;          // 0..6143 (1536 blocks)
    unsigned int voff = (unsigned int)wave_gid * 32768u + (unsigned int)lane * 16u;

    const float* realp = real;
    const float* fakep = fake;

    float s0 = 0.0f, s1 = 0.0f;

    f32x4 rA0, rA1, rA2, rA3, fA0, fA1, fA2, fA3;
    f32x4 rB0, rB1, rB2, rB3, fB0, fB1, fB2, fB3;

#define CP(r, f) { s0 += bce2(r[0], f[0]); s1 += bce2(r[1], f[1]); \
                   s0 += bce2(r[2], f[2]); s1 += bce2(r[3], f[3]); }
#define CPA CP(rA0, fA0) CP(rA1, fA1) CP(rA2, fA2) CP(rA3, fA3)
#define CPB CP(rB0, fB0) CP(rB1, fB1) CP(rB2, fB2) CP(rB3, fB3)
#define ISSUE_A ISSUE(rA0, rA1, rA2, rA3, fA0, fA1, fA2, fA3)
#define ISSUE_B ISSUE(rB0, rB1, rB2, rB3, fB0, fB1, fB2, fB3)

    ISSUE_A; voff += 4096u;             // batch 0 in flight (8 loads)
    ISSUE_B; voff += 4096u;             // batch 1 in flight (16 loads)
    WAIT8 CPA ISSUE_A; voff += 4096u;   // compute 0, issue 2
    WAIT8 CPB ISSUE_B; voff += 4096u;   // compute 1, issue 3
    WAIT8 CPA ISSUE_A; voff += 4096u;   // compute 2, issue 4
    WAIT8 CPB ISSUE_B; voff += 4096u;   // compute 3, issue 5
    WAIT8 CPA ISSUE_A; voff += 4096u;   // compute 4, issue 6
    WAIT8 CPB ISSUE_B;                  // compute 5, issue 7
    WAIT8 CPA                           // compute 6
    WAIT0 CPB                           // compute 7

#undef CP
#undef CPA
#undef CPB
#undef ISSUE_A
#undef ISSUE_B

    float s = s0 + s1;

    // wave-64 reduce
    #pragma unroll
    for (int o = 32; o > 0; o >>= 1) s += __shfl_down(s, o, 64);

    __shared__ float wsum[4];
    if (lane == 0) wsum[wid] = s;
    __syncthreads();
    if (threadIdx.x == 0) {
        float t = wsum[0] + wsum[1] + wsum[2] + wsum[3];
        atomicAdd(&acc[0], (double)t);
    }
}

__global__ __launch_bounds__(128) void latent_kernel(
    const float* __restrict__ mean, const float* __restrict__ logvar,
    const float* __restrict__ am,   const float* __restrict__ al,
    const float* __restrict__ pm,   const float* __restrict__ pl,
    const float* __restrict__ nm,   const float* __restrict__ nl,
    double* __restrict__ acc)
{
    const int b   = blockIdx.x;
    const int j   = threadIdx.x;      // 0..127 latent dim
    const int idx = b * DLAT + j;

    const float m  = mean[idx];
    const float lv = logvar[idx];
    const float kl_p = 1.0f + lv - m * m - expf(lv);

    const float amj = am[idx], alj = al[idx];
    const float pmj = pm[idx], plj = pl[idx];
    const float nmj = nm[idx], nlj = nl[idx];
    const float va  = expf(alj);

    // term_a + term_b = 2*log(vm) - la - lb + 2 + 0.5*(ma-mb)^2/vm
    const float vp   = expf(plj);
    const float vm_p = 0.25f * (va + vp);
    const float dmp  = amj - pmj;
    const float s_ap = 2.0f * logf(vm_p) - alj - plj + 2.0f + 0.5f * dmp * dmp / vm_p;

    const float vn   = expf(nlj);
    const float vm_n = 0.25f * (va + vn);
    const float dmn  = amj - nmj;
    const float s_an = 2.0f * logf(vm_n) - alj - nlj + 2.0f + 0.5f * dmn * dmn / vm_n;

    float a = s_ap, c = s_an, k = kl_p;
    #pragma unroll
    for (int o = 32; o > 0; o >>= 1) {
        a += __shfl_down(a, o, 64);
        c += __shfl_down(c, o, 64);
        k += __shfl_down(k, o, 64);
    }
    __shared__ float red[2][3];
    const int lane = threadIdx.x & 63;
    const int wid  = threadIdx.x >> 6;
    if (lane == 0) { red[wid][0] = a; red[wid][1] = c; red[wid][2] = k; }
    __syncthreads();
    if (threadIdx.x == 0) {
        const float S_ap = red[0][0] + red[1][0];
        const float S_an = red[0][1] + red[1][1];
        const float S_kl = red[0][2] + red[1][2];
        const float js_ap = 0.25f * S_ap;
        const float js_an = 0.25f * S_an;
        const float prob  = 1.0f / (1.0f + expf(js_ap - js_an));
        atomicAdd(&acc[1], (double)S_kl);
        atomicAdd(&acc[2], (double)prob);
    }
}

__global__ void finalize_kernel(const double* __restrict__ acc, float* __restrict__ out)
{
    if (threadIdx.x == 0 && blockIdx.x == 0) {
        const double recon   = -(LN2 * acc[0] / (double)N_IMG);   // log2 -> ln
        const double kl      = -0.5 * (acc[1] / (double)(BATCH * DLAT));
        const double triplet = -(acc[2] / (double)BATCH);
        out[0] = (float)(recon + kl + triplet);  // final_loss
        out[1] = (float)triplet;                 // triplet_error
        out[2] = (float)recon;                   // recon_error
        out[3] = (float)kl;                      // kl_error
    }
}

extern "C" void kernel_launch(void* const* d_in, const int* in_sizes, int n_in,
                              void* d_out, int out_size, void* d_ws, size_t ws_size,
                              hipStream_t stream)
{
    const float* real = (const float*)d_in[0];
    const float* fake = (const float*)d_in[1];
    const float* mean = (const float*)d_in[2];
    const float* logv = (const float*)d_in[3];
    const float* am   = (const float*)d_in[4];
    const float* al   = (const float*)d_in[5];
    const float* pm   = (const float*)d_in[6];
    const float* pl   = (const float*)d_in[7];
    const float* nm   = (const float*)d_in[8];
    const float* nl   = (const float*)d_in[9];
    float*  out = (float*)d_out;
    double* acc = (double*)d_ws;

    (void)hipMemsetAsync(acc, 0, 3 * sizeof(double), stream);

    // 1536 blocks x 4 waves = 6144 waves x 32KB/stream = exactly 2 x 201.3MB.
    bce_reduce_kernel<<<1536, 256, 0, stream>>>(real, fake, &acc[0]);
    latent_kernel<<<BATCH, DLAT, 0, stream>>>(mean, logv, am, al, pm, pl, nm, nl, acc);
    finalize_kernel<<<1, 64, 0, stream>>>(acc, out);
}

// Round 11
// 66.677 us; speedup vs baseline: 1.8080x; 1.4732x over previous
//
#include <hip/hip_runtime.h>

// Problem constants (match reference)
#define N_IMG 50331648    // 1024*3*128*128 elements per image tensor
#define BATCH 1024
#define DLAT  128
#define LN2   0.69314718055994530942

#define BCE_BLOCKS 1536
#define LAT_BLOCKS 512          // 2 rows per block
// ws layout (floats, all fully overwritten every call -> no init needed):
//   ws[0..1535]        per-block BCE partials (log2 domain)
//   ws[1536..2047]     per-block KL partials (2 rows each)
//   ws[2048..2559]     per-block prob partials (2 rows each)
#define WS_KL   BCE_BLOCKS
#define WS_PROB (BCE_BLOCKS + LAT_BLOCKS)

typedef float f32x4 __attribute__((ext_vector_type(4)));

// BCE element in log2 domain: lg + r*(lf - lg), lf=log2(f), lg=log2(1-f).
__device__ __forceinline__ float bce2(float r, float f) {
    const float lf = __log2f(f);
    const float lg = __log2f(1.0f - f);
    return lg + r * (lf - lg);
}

// R10 post-mortem: {MLP x cache-policy} grid complete. With NT(real-only)
// partitioning, paired reads converge at ~4.4 TB/s composite (2.2 HBM +
// 2.2 MALL) across three codegens; forced 16-deep MLP adds only ~3%.
// BCE core is at its pattern ceiling. This round removes the remaining
// serial overhead: memset + latent launch + atomics + extra dispatch.
#define ISSUE(r0,r1,r2,r3,g0,g1,g2,g3)                      \
  asm volatile(                                             \
    "global_load_dwordx4 %0, %8, %9 offset:0 nt\n\t"        \
    "global_load_dwordx4 %1, %8, %9 offset:1024 nt\n\t"     \
    "global_load_dwordx4 %2, %8, %9 offset:2048 nt\n\t"     \
    "global_load_dwordx4 %3, %8, %9 offset:3072 nt\n\t"     \
    "global_load_dwordx4 %4, %8, %10 offset:0\n\t"          \
    "global_load_dwordx4 %5, %8, %10 offset:1024\n\t"       \
    "global_load_dwordx4 %6, %8, %10 offset:2048\n\t"       \
    "global_load_dwordx4 %7, %8, %10 offset:3072"           \
    : "=&v"(r0), "=&v"(r1), "=&v"(r2), "=&v"(r3),           \
      "=&v"(g0), "=&v"(g1), "=&v"(g2), "=&v"(g3)            \
    : "v"(voff), "s"(realp), "s"(fakep)                     \
    : "memory")

#define WAIT8 { asm volatile("s_waitcnt vmcnt(8)" ::: "memory"); \
                __builtin_amdgcn_sched_barrier(0); }
#define WAIT0 { asm volatile("s_waitcnt vmcnt(0)" ::: "memory"); \
                __builtin_amdgcn_sched_barrier(0); }

__global__ __launch_bounds__(256, 4) void fused_main_kernel(
    const float* __restrict__ real,
    const float* __restrict__ fake,
    const float* __restrict__ mean, const float* __restrict__ logvar,
    const float* __restrict__ am,   const float* __restrict__ al,
    const float* __restrict__ pm,   const float* __restrict__ pl,
    const float* __restrict__ nm,   const float* __restrict__ nl,
    float* __restrict__ ws)
{
    const int lane = threadIdx.x & 63;
    const int wid  = threadIdx.x >> 6;

    if (blockIdx.x < BCE_BLOCKS) {
        // ---------------- BCE role (R10 core, unchanged) ----------------
        const int wave_gid = blockIdx.x * 4 + wid;      // 0..6143
        unsigned int voff = (unsigned int)wave_gid * 32768u + (unsigned int)lane * 16u;

        const float* realp = real;
        const float* fakep = fake;

        float s0 = 0.0f, s1 = 0.0f;

        f32x4 rA0, rA1, rA2, rA3, fA0, fA1, fA2, fA3;
        f32x4 rB0, rB1, rB2, rB3, fB0, fB1, fB2, fB3;

#define CP(r, f) { s0 += bce2(r[0], f[0]); s1 += bce2(r[1], f[1]); \
                   s0 += bce2(r[2], f[2]); s1 += bce2(r[3], f[3]); }
#define CPA CP(rA0, fA0) CP(rA1, fA1) CP(rA2, fA2) CP(rA3, fA3)
#define CPB CP(rB0, fB0) CP(rB1, fB1) CP(rB2, fB2) CP(rB3, fB3)
#define ISSUE_A ISSUE(rA0, rA1, rA2, rA3, fA0, fA1, fA2, fA3)
#define ISSUE_B ISSUE(rB0, rB1, rB2, rB3, fB0, fB1, fB2, fB3)

        ISSUE_A; voff += 4096u;
        ISSUE_B; voff += 4096u;
        WAIT8 CPA ISSUE_A; voff += 4096u;
        WAIT8 CPB ISSUE_B; voff += 4096u;
        WAIT8 CPA ISSUE_A; voff += 4096u;
        WAIT8 CPB ISSUE_B; voff += 4096u;
        WAIT8 CPA ISSUE_A; voff += 4096u;
        WAIT8 CPB ISSUE_B;
        WAIT8 CPA
        WAIT0 CPB

#undef CP
#undef CPA
#undef CPB
#undef ISSUE_A
#undef ISSUE_B

        float s = s0 + s1;
        #pragma unroll
        for (int o = 32; o > 0; o >>= 1) s += __shfl_down(s, o, 64);

        __shared__ float wsum[4];
        if (lane == 0) wsum[wid] = s;
        __syncthreads();
        if (threadIdx.x == 0)
            ws[blockIdx.x] = wsum[0] + wsum[1] + wsum[2] + wsum[3];
    } else {
        // ---------------- latent role: 2 batch-rows per block -----------
        const int lb  = blockIdx.x - BCE_BLOCKS;        // 0..511
        const int row = threadIdx.x >> 7;               // 0..1
        const int j   = threadIdx.x & 127;              // latent dim
        const int b   = lb * 2 + row;
        const int idx = b * DLAT + j;

        const float m  = mean[idx];
        const float lv = logvar[idx];
        const float kl_p = 1.0f + lv - m * m - expf(lv);

        const float amj = am[idx], alj = al[idx];
        const float pmj = pm[idx], plj = pl[idx];
        const float nmj = nm[idx], nlj = nl[idx];
        const float va  = expf(alj);

        // term_a + term_b = 2*log(vm) - la - lb + 2 + 0.5*(ma-mb)^2/vm
        const float vp   = expf(plj);
        const float vm_p = 0.25f * (va + vp);
        const float dmp  = amj - pmj;
        const float s_ap = 2.0f * logf(vm_p) - alj - plj + 2.0f + 0.5f * dmp * dmp / vm_p;

        const float vn   = expf(nlj);
        const float vm_n = 0.25f * (va + vn);
        const float dmn  = amj - nmj;
        const float s_an = 2.0f * logf(vm_n) - alj - nlj + 2.0f + 0.5f * dmn * dmn / vm_n;

        float a = s_ap, c = s_an, k = kl_p;
        #pragma unroll
        for (int o = 32; o > 0; o >>= 1) {
            a += __shfl_down(a, o, 64);
            c += __shfl_down(c, o, 64);
            k += __shfl_down(k, o, 64);
        }
        __shared__ float red[4][3];       // per-wave partials
        __shared__ float rowres[2][2];    // per-row {prob, kl}
        if (lane == 0) { red[wid][0] = a; red[wid][1] = c; red[wid][2] = k; }
        __syncthreads();
        if ((threadIdx.x & 127) == 0) {   // one leader per row (tid 0, 128)
            const int w0 = row * 2;
            const float S_ap = red[w0][0] + red[w0 + 1][0];
            const float S_an = red[w0][1] + red[w0 + 1][1];
            const float S_kl = red[w0][2] + red[w0 + 1][2];
            // prob = 1/(1+exp(js_ap - js_an)), js = 0.25*S
            rowres[row][0] = 1.0f / (1.0f + expf(0.25f * S_ap - 0.25f * S_an));
            rowres[row][1] = S_kl;
        }
        __syncthreads();
        if (threadIdx.x == 0) {
            ws[WS_KL   + lb] = rowres[0][1] + rowres[1][1];
            ws[WS_PROB + lb] = rowres[0][0] + rowres[1][0];
        }
    }
}

__global__ __launch_bounds__(1024) void finalize_kernel(
    const float* __restrict__ ws, float* __restrict__ out)
{
    const int t = threadIdx.x;
    double sb = 0.0, sk = 0.0, sp = 0.0;
    for (int i = t; i < BCE_BLOCKS; i += 1024) sb += (double)ws[i];
    if (t < LAT_BLOCKS) {
        sk = (double)ws[WS_KL   + t];
        sp = (double)ws[WS_PROB + t];
    }
    // wave reduce (doubles), then LDS combine across 16 waves
    #pragma unroll
    for (int o = 32; o > 0; o >>= 1) {
        sb += __shfl_down(sb, o, 64);
        sk += __shfl_down(sk, o, 64);
        sp += __shfl_down(sp, o, 64);
    }
    __shared__ double red[16][3];
    const int lane = t & 63;
    const int wid  = t >> 6;
    if (lane == 0) { red[wid][0] = sb; red[wid][1] = sk; red[wid][2] = sp; }
    __syncthreads();
    if (t == 0) {
        double B = 0.0, K = 0.0, P = 0.0;
        #pragma unroll
        for (int w = 0; w < 16; ++w) { B += red[w][0]; K += red[w][1]; P += red[w][2]; }
        const double recon   = -(LN2 * B / (double)N_IMG);   // log2 -> ln
        const double kl      = -0.5 * (K / (double)(BATCH * DLAT));
        const double triplet = -(P / (double)BATCH);
        out[0] = (float)(recon + kl + triplet);  // final_loss
        out[1] = (float)triplet;                 // triplet_error
        out[2] = (float)recon;                   // recon_error
        out[3] = (float)kl;                      // kl_error
    }
}

extern "C" void kernel_launch(void* const* d_in, const int* in_sizes, int n_in,
                              void* d_out, int out_size, void* d_ws, size_t ws_size,
                              hipStream_t stream)
{
    const float* real = (const float*)d_in[0];
    const float* fake = (const float*)d_in[1];
    const float* mean = (const float*)d_in[2];
    const float* logv = (const float*)d_in[3];
    const float* am   = (const float*)d_in[4];
    const float* al   = (const float*)d_in[5];
    const float* pm   = (const float*)d_in[6];
    const float* pl   = (const float*)d_in[7];
    const float* nm   = (const float*)d_in[8];
    const float* nl   = (const float*)d_in[9];
    float* out = (float*)d_out;
    float* ws  = (float*)d_ws;

    // Two dispatches total; every ws slot is plain-stored each call (no
    // memset, no atomics, deterministic across replays).
    fused_main_kernel<<<BCE_BLOCKS + LAT_BLOCKS, 256, 0, stream>>>(
        real, fake, mean, logv, am, al, pm, pl, nm, nl, ws);
    finalize_kernel<<<1, 1024, 0, stream>>>(ws, out);
}